// Round 9
// baseline (40.500 us; speedup 1.0000x reference)
//
#include <hip/hip_runtime.h>

#define ALPHA 0.05f

typedef float f32x4 __attribute__((ext_vector_type(4)));
typedef float f32x2 __attribute__((ext_vector_type(2)));

// Tile 64 wide x 32 tall, halo 8 (+1 for x1/y1 tap). Staged I2 region:
// 84 cols x 49 rows = 21 f32x4-chunks/row, staged via global_load_lds
// (linear LDS dest = wave base + lane*16), clamped per-lane source.
// NOTE: halo must be ≡ 0 mod 4 so the 16B chunk grid aligns with the
// gx<=508 clamp (clamp-shifted chunks then only cover weight-0/never-read
// cells). halo=8 satisfies this.
constexpr int RW = 84, RH = 49;
constexpr int LDS_FLOATS = 5 * 256 * 4; // 5120 (pass 4 tail = harmless dup work)

__global__ __launch_bounds__(256) void dataterm_kernel(
    const float* __restrict__ I1,
    const float* __restrict__ I2,
    const float* __restrict__ flow,
    float* __restrict__ out)
{
    __shared__ float s_i2[LDS_FLOATS];

    int blk = blockIdx.x;
    int tx0 = (blk & 7) << 6;            // 8 x-tiles
    int ty0 = ((blk >> 3) & 15) << 5;    // 16 y-tiles
    int b   = blk >> 7;                  // 32 images
    int base = b << 18;

    const float* I2b = I2 + base;
    const float* I1b = I1 + base;
    int tid = threadIdx.x;

    // ---- thread geometry: 32 x-lanes (2 px each) x 4 consecutive rows ----
    int lx = tid & 31;
    int rg = tid >> 5;                   // row group 0..7
    int x  = tx0 + (lx << 1);            // even x
    int yb = ty0 + (rg << 2);            // first of this thread's 4 rows
    int pix0 = (yb << 9) + x;

    // ---- prefetch flow + I1 into registers (latency hides under staging) ----
    f32x4 fA[4];
    f32x2 rowv[5];
    float i1n[4];
#pragma unroll
    for (int j = 0; j < 4; ++j)
        fA[j] = *reinterpret_cast<const f32x4*>(flow + 2 * (base + pix0 + (j << 9)));
#pragma unroll
    for (int j = 0; j < 4; ++j)
        rowv[j] = *reinterpret_cast<const f32x2*>(I1b + pix0 + (j << 9));
    // 5th row: only OOB when yb+3 == 511; reuse -> dy row 511 = 0 exactly
    rowv[4] = (yb + 4 < 512)
        ? *reinterpret_cast<const f32x2*>(I1b + pix0 + (4 << 9)) : rowv[3];
#pragma unroll
    for (int j = 0; j < 4; ++j)
        i1n[j] = (x < 510) ? I1b[pix0 + (j << 9) + 2] : 0.0f;

    // ---- stage I2 region: async global->LDS, clamped per-lane source ----
    // Clamped (duplicated) cells are either never read or read only by
    // weight-0 taps (reference clamps coords before floor).
    int wave = tid >> 6;
    int lane = tid & 63;
#pragma unroll
    for (int p = 0; p < 5; ++p) {
        int cb = (p << 8) + (wave << 6);          // wave-uniform chunk base
        int i  = cb + lane;
        int r  = i / 21;
        int c4 = (i - r * 21) << 2;
        int sy = min(max(ty0 - 8 + r, 0), 511);
        int gx = min(max(tx0 - 8 + c4, 0), 508);
        const float* g = I2b + (sy << 9) + gx;
        __builtin_amdgcn_global_load_lds(
            (const __attribute__((address_space(1))) void*)g,
            (__attribute__((address_space(3))) void*)(s_i2 + (cb << 2)),
            16, 0, 0);
    }
    __syncthreads();

    // ---- compute: 2 px x 4 rows per thread, all inputs in regs/LDS ----
#pragma unroll
    for (int j = 0; j < 4; ++j) {
        int y   = yb + j;
        int pix = pix0 + (j << 9);

        float ua[2] = { fA[j].x, fA[j].z };
        float va[2] = { fA[j].y, fA[j].w };
        float i1a[2]  = { rowv[j].x, rowv[j].y };
        float i1ra[2] = { rowv[j].y, i1n[j] };
        float i1ba[2] = { rowv[j + 1].x, rowv[j + 1].y };
        float un[2], vn[2];

#pragma unroll
        for (int k = 0; k < 2; ++k) {
            int xk = x + k;
            float u = ua[k], v = va[k];
            // reference naming swap: "grad_x" = vertical diff, "grad_y" = horizontal
            float g_dy = i1ba[k] - i1a[k];            // rowv[4]==rowv[3] at y==511
            float g_dx = (xk < 511) ? (i1ra[k] - i1a[k]) : 0.0f;

            float xx = fminf(fmaxf((float)xk + u, 0.0f), 511.0f);
            float yy = fminf(fmaxf((float)y  + v, 0.0f), 511.0f);
            float x0f = floorf(xx);
            float y0f = floorf(yy);
            int x0 = (int)x0f;
            int y0 = (int)y0f;
            float wx = xx - x0f;
            float wy = yy - y0f;

            float Ia, Ib_, Ic, Id;
            bool oob = fmaxf(fabsf(u), fabsf(v)) > 8.0f;
            if (__builtin_expect(!oob, 1)) {
                int lidx = (y0 - ty0 + 8) * RW + (x0 - tx0 + 8);
                Ia  = s_i2[lidx];
                Ib_ = s_i2[lidx + 1];
                Ic  = s_i2[lidx + RW];
                Id  = s_i2[lidx + RW + 1];
            } else {
                int x1 = min(x0 + 1, 511);
                int y1 = min(y0 + 1, 511);
                Ia  = I2b[(y0 << 9) + x0];
                Ib_ = I2b[(y0 << 9) + x1];
                Ic  = I2b[(y1 << 9) + x0];
                Id  = I2b[(y1 << 9) + x1];
            }

            float top = Ia + wx * (Ib_ - Ia);
            float bot = Ic + wx * (Id - Ic);
            float warped = top + wy * (bot - top);

            float dt = warped - i1a[k];
            un[k] = u - ALPHA * dt * g_dy;
            vn[k] = v - ALPHA * dt * g_dx;
        }

        // plain (allocating) store: let output lines live in L2/L3 so timed
        // replays re-dirty resident lines instead of streaming to HBM
        f32x4 ov;
        ov.x = un[0]; ov.y = vn[0]; ov.z = un[1]; ov.w = vn[1];
        *reinterpret_cast<f32x4*>(out + 2 * (base + pix)) = ov;
    }
}

extern "C" void kernel_launch(void* const* d_in, const int* in_sizes, int n_in,
                              void* d_out, int out_size, void* d_ws, size_t ws_size,
                              hipStream_t stream) {
    const float* I1   = (const float*)d_in[0];
    const float* I2   = (const float*)d_in[1];
    const float* flow = (const float*)d_in[2];
    float* out = (float*)d_out;

    // 32 images x (8 x-tiles) x (16 y-tiles) = 4096 blocks
    dataterm_kernel<<<4096, 256, 0, stream>>>(I1, I2, flow, out);
}

// Round 10
// 35.384 us; speedup vs baseline: 1.1446x; 1.1446x over previous
//
#include <hip/hip_runtime.h>

#define ALPHA 0.05f

typedef float f32x4 __attribute__((ext_vector_type(4)));
typedef float f32x2 __attribute__((ext_vector_type(2)));

// Tile 64 wide x 64 tall, halo 8 (+1 for x1/y1 tap). Staged I2 region:
// 84 cols x 81 rows = 21 f32x4-chunks/row = 1701 chunks, staged via
// global_load_lds in 7 passes of 256 chunks (linear LDS dest), clamped
// per-lane global source. Clamp-duplicated cells are either never read or
// read only by weight-0 taps (reference clamps coords before floor), or
// (bottom row) exactly equal to the reference's clamped y1 row.
constexpr int RW = 84, RH = 81;
constexpr int NPASS = 7;
constexpr int LDS_FLOATS = NPASS * 256 * 4;   // 7168 floats = 28.7 KB

__global__ __launch_bounds__(256) void dataterm_kernel(
    const float* __restrict__ I1,
    const float* __restrict__ I2,
    const float* __restrict__ flow,
    float* __restrict__ out)
{
    __shared__ float s_i2[LDS_FLOATS];

    // XCD-chunked swizzle (T1): dispatch d -> xcd d%8 executes contiguous
    // original blocks [xcd*256, xcd*256+256) = 4 complete images -> halo
    // sharing between neighbor tiles stays within one XCD's L2.
    int d   = blockIdx.x;
    int blk = ((d & 7) << 8) | (d >> 3);
    int tx0 = (blk & 7) << 6;            // 8 x-tiles
    int ty0 = ((blk >> 3) & 7) << 6;     // 8 y-tiles
    int b   = blk >> 6;                  // 32 images
    int base = b << 18;

    const float* I2b = I2 + base;
    const float* I1b = I1 + base;
    int tid = threadIdx.x;

    // ---- stage I2 region: async global->LDS, clamped per-lane source ----
    int wave = tid >> 6;
    int lane = tid & 63;
#pragma unroll
    for (int p = 0; p < NPASS; ++p) {
        int cb = (p << 8) + (wave << 6);          // wave-uniform chunk base
        int i  = cb + lane;
        int r  = i / 21;
        int c4 = (i - r * 21) << 2;
        int sy = min(max(ty0 - 8 + r, 0), 511);
        int gx = min(max(tx0 - 8 + c4, 0), 508);
        const float* g = I2b + (sy << 9) + gx;
        __builtin_amdgcn_global_load_lds(
            (const __attribute__((address_space(1))) void*)g,
            (__attribute__((address_space(3))) void*)(s_i2 + (cb << 2)),
            16, 0, 0);
    }

    // ---- thread geometry: 32 x-lanes (2 px each) x 4 consecutive rows,
    //      two half-tiles (rows +0 and +32) ----
    int lx = tid & 31;
    int rg = tid >> 5;                   // row group 0..7
    int x  = tx0 + (lx << 1);            // even x

    for (int h = 0; h < 2; ++h) {
        int yb = ty0 + (rg << 2) + (h << 5);      // first of this half's 4 rows
        int pix0 = (yb << 9) + x;

        // prefetch flow + I1 into registers (h=0 hides under staging,
        // h=1 hides under h=0 compute)
        f32x4 fA[4];
        f32x2 rowv[5];
        float i1n[4];
#pragma unroll
        for (int j = 0; j < 4; ++j)
            fA[j] = *reinterpret_cast<const f32x4*>(flow + 2 * (base + pix0 + (j << 9)));
#pragma unroll
        for (int j = 0; j < 4; ++j)
            rowv[j] = *reinterpret_cast<const f32x2*>(I1b + pix0 + (j << 9));
        rowv[4] = (yb + 4 < 512)
            ? *reinterpret_cast<const f32x2*>(I1b + pix0 + (4 << 9)) : rowv[3];
#pragma unroll
        for (int j = 0; j < 4; ++j)
            i1n[j] = (x < 510) ? I1b[pix0 + (j << 9) + 2] : 0.0f;

        if (h == 0) __syncthreads();     // staging complete before LDS reads

#pragma unroll
        for (int j = 0; j < 4; ++j) {
            int y   = yb + j;
            int pix = pix0 + (j << 9);

            float ua[2] = { fA[j].x, fA[j].z };
            float va[2] = { fA[j].y, fA[j].w };
            float i1a[2]  = { rowv[j].x, rowv[j].y };
            float i1ra[2] = { rowv[j].y, i1n[j] };
            float i1ba[2] = { rowv[j + 1].x, rowv[j + 1].y };
            float un[2], vn[2];

#pragma unroll
            for (int k = 0; k < 2; ++k) {
                int xk = x + k;
                float u = ua[k], v = va[k];
                // reference naming swap: "grad_x" = vertical, "grad_y" = horizontal
                float g_dy = i1ba[k] - i1a[k];        // rowv[4]==rowv[3] at y==511
                float g_dx = (xk < 511) ? (i1ra[k] - i1a[k]) : 0.0f;

                float xx = fminf(fmaxf((float)xk + u, 0.0f), 511.0f);
                float yy = fminf(fmaxf((float)y  + v, 0.0f), 511.0f);
                float x0f = floorf(xx);
                float y0f = floorf(yy);
                int x0 = (int)x0f;
                int y0 = (int)y0f;
                float wx = xx - x0f;
                float wy = yy - y0f;

                float Ia, Ib_, Ic, Id;
                bool oob = fmaxf(fabsf(u), fabsf(v)) > 8.0f;
                if (__builtin_expect(!oob, 1)) {
                    int lidx = (y0 - ty0 + 8) * RW + (x0 - tx0 + 8);
                    Ia  = s_i2[lidx];
                    Ib_ = s_i2[lidx + 1];
                    Ic  = s_i2[lidx + RW];
                    Id  = s_i2[lidx + RW + 1];
                } else {
                    int x1 = min(x0 + 1, 511);
                    int y1 = min(y0 + 1, 511);
                    Ia  = I2b[(y0 << 9) + x0];
                    Ib_ = I2b[(y0 << 9) + x1];
                    Ic  = I2b[(y1 << 9) + x0];
                    Id  = I2b[(y1 << 9) + x1];
                }

                float top = Ia + wx * (Ib_ - Ia);
                float bot = Ic + wx * (Id - Ic);
                float warped = top + wy * (bot - top);

                float dt = warped - i1a[k];
                un[k] = u - ALPHA * dt * g_dy;
                vn[k] = v - ALPHA * dt * g_dx;
            }

            f32x4 ov;
            ov.x = un[0]; ov.y = vn[0]; ov.z = un[1]; ov.w = vn[1];
            __builtin_nontemporal_store(ov,
                reinterpret_cast<f32x4*>(out + 2 * (base + pix)));
        }
    }
}

extern "C" void kernel_launch(void* const* d_in, const int* in_sizes, int n_in,
                              void* d_out, int out_size, void* d_ws, size_t ws_size,
                              hipStream_t stream) {
    const float* I1   = (const float*)d_in[0];
    const float* I2   = (const float*)d_in[1];
    const float* flow = (const float*)d_in[2];
    float* out = (float*)d_out;

    // 32 images x (8 x-tiles) x (8 y-tiles) = 2048 blocks
    dataterm_kernel<<<2048, 256, 0, stream>>>(I1, I2, flow, out);
}